// Round 4
// baseline (229.042 us; speedup 1.0000x reference)
//
#include <hip/hip_runtime.h>

#define SLEN 4096
#define DDIM 128
#define BATCH 4
#define QB 512
#define NQB (SLEN / QB)        // 8 q-blocks per batch
#define NW 8                   // waves per attn block (512 threads)
#define KSPLIT 16              // k-range split across blocks
#define NTILES (SLEN / 16)     // 256 k-tiles
#define TPB (NTILES / KSPLIT)  // 16 tiles per block
#define STAGE_TILES 4          // tiles per LDS stage (16 KB)
#define NSTAGES (TPB / STAGE_TILES)  // 4
#define WSLABS (NQB * NW)      // 64 colsum slabs per batch
#define SCLOG2E 0.12751743f    // log2(e)/sqrt(128)

typedef __bf16 v8bf __attribute__((ext_vector_type(8)));
typedef float f32x4 __attribute__((ext_vector_type(4)));

__device__ __forceinline__ f32x4 mfma16(v8bf a, v8bf b, f32x4 c) {
  return __builtin_amdgcn_mfma_f32_16x16x32_bf16(a, b, c, 0, 0, 0);
}

__device__ __forceinline__ void gload_lds16(const void* g, void* l) {
  __builtin_amdgcn_global_load_lds(
      (const __attribute__((address_space(1))) unsigned int*)g,
      (__attribute__((address_space(3))) unsigned int*)l, 16, 0, 0);
}

// Stage 4 K-tiles (64 rows x 256B) into LDS, XOR-swizzled.
// LDS slot s (16B units): row r = s>>4, phys slot p = s&15 holds logical slot
// p ^ (r&7) of row r. global_load_lds dest = wave-uniform base + lane*16, so
// the swizzle is applied on the per-lane GLOBAL source address (rule #21).
__device__ __forceinline__ void stage_k(const __bf16* __restrict__ Krow0,
                                        char* buf, int wave, int lane) {
#pragma unroll
  for (int i = 0; i < 2; ++i) {
    int s = i * 512 + wave * 64 + lane;
    int r = s >> 4;
    int p = s & 15;
    int lsl = p ^ (r & 7);
    const __bf16* src = Krow0 + (size_t)r * DDIM + lsl * 8;
    char* dst = buf + (size_t)(i * 512 + wave * 64) * 16;  // wave-uniform
    gload_lds16(src, dst);
  }
}

// ---------------------------------------------------------------------------
// k0: pack Wq|Wk columns into MFMA B-fragment layout, bf16.
__global__ __launch_bounds__(256) void k0_wt(const float* __restrict__ Wq,
                                             const float* __restrict__ Wk,
                                             __bf16* __restrict__ Wt) {
  int idx = blockIdx.x * 256 + threadIdx.x;   // 0..4095
  int ct = idx >> 8;
  int hs = (idx >> 6) & 3;
  int l  = idx & 63;
  int col = ((ct & 7) << 4) + (l & 15);
  const float* W = (ct < 8) ? Wq : Wk;
  int hbase = hs * 32 + (l >> 4) * 8;
  __bf16* dst = Wt + (size_t)idx * 8;
  for (int i = 0; i < 8; ++i)
    dst[i] = (__bf16)W[(hbase + i) * DDIM + col];
}

// ---------------------------------------------------------------------------
// k1: projections Q = x@Wq + bq, K = x@Wk + bk  -> bf16, via MFMA.
__global__ __launch_bounds__(256) void k1_proj(const float* __restrict__ x,
                                               const __bf16* __restrict__ Wt,
                                               const float* __restrict__ bq,
                                               const float* __restrict__ bk,
                                               __bf16* __restrict__ Qb,
                                               __bf16* __restrict__ Kb) {
  int wave = threadIdx.x >> 6, lane = threadIdx.x & 63;
  int lr = lane & 15, lg = lane >> 4;
  int r0 = blockIdx.x * 64 + wave * 16;      // flat row over B*S
  const float* xrow = x + (size_t)(r0 + lr) * DDIM;

  v8bf xf[4];
#pragma unroll
  for (int hs = 0; hs < 4; ++hs) {
    float4 a = *reinterpret_cast<const float4*>(xrow + hs * 32 + lg * 8);
    float4 c = *reinterpret_cast<const float4*>(xrow + hs * 32 + lg * 8 + 4);
    v8bf t;
    t[0] = (__bf16)a.x; t[1] = (__bf16)a.y; t[2] = (__bf16)a.z; t[3] = (__bf16)a.w;
    t[4] = (__bf16)c.x; t[5] = (__bf16)c.y; t[6] = (__bf16)c.z; t[7] = (__bf16)c.w;
    xf[hs] = t;
  }

  for (int ct = 0; ct < 16; ++ct) {
    f32x4 acc = {0.f, 0.f, 0.f, 0.f};
#pragma unroll
    for (int hs = 0; hs < 4; ++hs) {
      v8bf wf = *reinterpret_cast<const v8bf*>(Wt + ((size_t)(ct * 4 + hs) * 64 + lane) * 8);
      acc = mfma16(xf[hs], wf, acc);
    }
    int col = ((ct & 7) << 4) + lr;
    float bias = (ct < 8) ? bq[col] : bk[col];
    __bf16* dst = (ct < 8) ? Qb : Kb;
#pragma unroll
    for (int j = 0; j < 4; ++j) {
      int row = r0 + lg * 4 + j;
      dst[(size_t)row * DDIM + col] = (__bf16)(acc[j] + bias);
    }
  }
}

// ---------------------------------------------------------------------------
// k2a: partial softmax denominators. Block (qblk,b,ks): 512 q-rows (8 waves x
// 64 disjoint rows), k-tiles [ks*TPB, (ks+1)*TPB) staged in LDS shared by all
// waves, double-buffered.
__global__ __launch_bounds__(512, 4) void k2a_z(const __bf16* __restrict__ Qb,
                                                const __bf16* __restrict__ Kb,
                                                float* __restrict__ zpart) {
  int b = blockIdx.y, qblk = blockIdx.x, ks = blockIdx.z;
  int wave = threadIdx.x >> 6, lane = threadIdx.x & 63;
  int lr = lane & 15, lg = lane >> 4;

  __shared__ __align__(16) char kbuf[2][STAGE_TILES * 16 * 256];

  const __bf16* Qbase = Qb + ((size_t)b * SLEN + qblk * QB + wave * 64) * DDIM;
  const __bf16* Kbase = Kb + ((size_t)b * SLEN + ks * TPB * 16) * DDIM;

  stage_k(Kbase, kbuf[0], wave, lane);

  v8bf qf[4][4];
#pragma unroll
  for (int qs = 0; qs < 4; ++qs)
#pragma unroll
    for (int hs = 0; hs < 4; ++hs)
      qf[qs][hs] = *reinterpret_cast<const v8bf*>(Qbase + (size_t)(qs * 16 + lr) * DDIM + hs * 32 + lg * 8);

  float zacc[4][4];
#pragma unroll
  for (int qs = 0; qs < 4; ++qs)
#pragma unroll
    for (int j = 0; j < 4; ++j) zacc[qs][j] = 0.f;

  __syncthreads();

  for (int s = 0; s < NSTAGES; ++s) {
    if (s + 1 < NSTAGES)
      stage_k(Kbase + (size_t)(s + 1) * STAGE_TILES * 16 * DDIM, kbuf[(s + 1) & 1], wave, lane);
    const char* buf = kbuf[s & 1];
#pragma unroll
    for (int t = 0; t < STAGE_TILES; ++t) {
      int r = t * 16 + lr;
      int rowbase = r * 256;
      f32x4 acc[4];
#pragma unroll
      for (int qs = 0; qs < 4; ++qs) acc[qs] = (f32x4){0.f, 0.f, 0.f, 0.f};
#pragma unroll
      for (int hs = 0; hs < 4; ++hs) {
        int slot = (hs * 4 + lg) ^ (r & 7);
        v8bf kc = *reinterpret_cast<const v8bf*>(buf + rowbase + slot * 16);
#pragma unroll
        for (int qs = 0; qs < 4; ++qs) acc[qs] = mfma16(qf[qs][hs], kc, acc[qs]);
      }
#pragma unroll
      for (int qs = 0; qs < 4; ++qs)
#pragma unroll
        for (int j = 0; j < 4; ++j)
          zacc[qs][j] += exp2f(acc[qs][j] * SCLOG2E);
    }
    __syncthreads();
  }

  // reduce over the 16 lr lanes (k columns); rows are wave-disjoint
#pragma unroll
  for (int qs = 0; qs < 4; ++qs)
#pragma unroll
    for (int j = 0; j < 4; ++j) {
      float z = zacc[qs][j];
      z += __shfl_xor(z, 1);
      z += __shfl_xor(z, 2);
      z += __shfl_xor(z, 4);
      z += __shfl_xor(z, 8);
      if (lr == 0)
        zpart[(((size_t)b * NQB + qblk) * KSPLIT + ks) * QB + wave * 64 + qs * 16 + lg * 4 + j] = z;
    }
}

// ---------------------------------------------------------------------------
// k2c: column weights w[k] = sum_q exp(s)/Z over this block's k-range.
__global__ __launch_bounds__(512, 4) void k2c_w(const __bf16* __restrict__ Qb,
                                                const __bf16* __restrict__ Kb,
                                                const float* __restrict__ zpart,
                                                __bf16* __restrict__ wpart) {
  int b = blockIdx.y, qblk = blockIdx.x, ks = blockIdx.z;
  int wave = threadIdx.x >> 6, lane = threadIdx.x & 63;
  int lr = lane & 15, lg = lane >> 4;

  __shared__ __align__(16) char kbuf[2][STAGE_TILES * 16 * 256];
  __shared__ float invZ[QB];

  const __bf16* Qbase = Qb + ((size_t)b * SLEN + qblk * QB + wave * 64) * DDIM;
  const __bf16* Kbase = Kb + ((size_t)b * SLEN + ks * TPB * 16) * DDIM;

  stage_k(Kbase, kbuf[0], wave, lane);

  v8bf qf[4][4];
#pragma unroll
  for (int qs = 0; qs < 4; ++qs)
#pragma unroll
    for (int hs = 0; hs < 4; ++hs)
      qf[qs][hs] = *reinterpret_cast<const v8bf*>(Qbase + (size_t)(qs * 16 + lr) * DDIM + hs * 32 + lg * 8);

  {
    const float* zp = zpart + ((size_t)b * NQB + qblk) * KSPLIT * QB + threadIdx.x;
    float z = 0.f;
#pragma unroll
    for (int s = 0; s < KSPLIT; ++s) z += zp[(size_t)s * QB];
    invZ[threadIdx.x] = 1.0f / z;
  }

  __syncthreads();

  float iz[4][4];
#pragma unroll
  for (int qs = 0; qs < 4; ++qs)
#pragma unroll
    for (int j = 0; j < 4; ++j)
      iz[qs][j] = invZ[wave * 64 + qs * 16 + lg * 4 + j];

  __bf16* wrow = wpart + ((size_t)b * WSLABS + qblk * NW + wave) * SLEN + ks * TPB * 16;

  for (int s = 0; s < NSTAGES; ++s) {
    if (s + 1 < NSTAGES)
      stage_k(Kbase + (size_t)(s + 1) * STAGE_TILES * 16 * DDIM, kbuf[(s + 1) & 1], wave, lane);
    const char* buf = kbuf[s & 1];
#pragma unroll
    for (int t = 0; t < STAGE_TILES; ++t) {
      int r = t * 16 + lr;
      int rowbase = r * 256;
      f32x4 acc[4];
#pragma unroll
      for (int qs = 0; qs < 4; ++qs) acc[qs] = (f32x4){0.f, 0.f, 0.f, 0.f};
#pragma unroll
      for (int hs = 0; hs < 4; ++hs) {
        int slot = (hs * 4 + lg) ^ (r & 7);
        v8bf kc = *reinterpret_cast<const v8bf*>(buf + rowbase + slot * 16);
#pragma unroll
        for (int qs = 0; qs < 4; ++qs) acc[qs] = mfma16(qf[qs][hs], kc, acc[qs]);
      }
      float wk = 0.f;
#pragma unroll
      for (int qs = 0; qs < 4; ++qs)
#pragma unroll
        for (int j = 0; j < 4; ++j)
          wk += exp2f(acc[qs][j] * SCLOG2E) * iz[qs][j];
      wk += __shfl_xor(wk, 16);
      wk += __shfl_xor(wk, 32);
      if (lg == 0)
        wrow[(s * STAGE_TILES + t) * 16 + lr] = (__bf16)wk;  // disjoint per wave slab
    }
    __syncthreads();
  }
}

// ---------------------------------------------------------------------------
// k4: fused column-sum + weighted x reduction.
__global__ __launch_bounds__(128) void k4_u(const float* __restrict__ x,
                                            const __bf16* __restrict__ wpart,
                                            float* __restrict__ upart) {
  int b = blockIdx.y, c = blockIdx.x, d = threadIdx.x;
  __shared__ float ws[128];
  const __bf16* p = wpart + (size_t)b * WSLABS * SLEN + c * 128 + d;
  float s = 0.f;
  for (int j = 0; j < WSLABS; ++j) s += (float)p[(size_t)j * SLEN];
  ws[d] = s;
  __syncthreads();
  const float* xb = x + ((size_t)b * SLEN + c * 128) * DDIM;
  float acc = 0.f;
  for (int kk = 0; kk < 128; ++kk)
    acc += ws[kk] * xb[(size_t)kk * DDIM + d];
  upart[((size_t)b * 32 + c) * DDIM + d] = acc;
}

// ---------------------------------------------------------------------------
// k5: out[b,d] = (1/S) * (u[b,:] @ Wv[:,d]) + bv[d]
__global__ __launch_bounds__(128) void k5_out(const float* __restrict__ upart,
                                              const float* __restrict__ Wv,
                                              const float* __restrict__ bv,
                                              float* __restrict__ out) {
  int b = blockIdx.x, d = threadIdx.x;
  __shared__ float u[DDIM];
  float s = 0.f;
  for (int c = 0; c < 32; ++c) s += upart[((size_t)b * 32 + c) * DDIM + d];
  u[d] = s;
  __syncthreads();
  float acc = 0.f;
  for (int dp = 0; dp < DDIM; ++dp) acc += u[dp] * Wv[(size_t)dp * DDIM + d];
  out[b * DDIM + d] = acc * (1.0f / SLEN) + bv[d];
}

// ---------------------------------------------------------------------------
extern "C" void kernel_launch(void* const* d_in, const int* in_sizes, int n_in,
                              void* d_out, int out_size, void* d_ws, size_t ws_size,
                              hipStream_t stream) {
  const float* x  = (const float*)d_in[0];
  const float* Wq = (const float*)d_in[1];
  const float* bq = (const float*)d_in[2];
  const float* Wk = (const float*)d_in[3];
  const float* bk = (const float*)d_in[4];
  const float* Wv = (const float*)d_in[5];
  const float* bv = (const float*)d_in[6];
  float* out = (float*)d_out;

  char* ws = (char*)d_ws;
  __bf16* Qb    = (__bf16*)(ws);                                  // 4 MB
  __bf16* Kb    = (__bf16*)(ws + (4u << 20));                     // 4 MB
  __bf16* Wt    = (__bf16*)(ws + (8u << 20));                     // 64 KB
  __bf16* wpart = (__bf16*)(ws + (8u << 20) + (128u << 10));      // 2 MB (bf16)
  float*  zpart = (float*)(ws + (10u << 20) + (128u << 10));      // 1 MB
  float*  upart = (float*)(ws + (11u << 20) + (256u << 10));      // 16 KB

  k0_wt  <<<16, 256, 0, stream>>>(Wq, Wk, Wt);
  k1_proj<<<256, 256, 0, stream>>>(x, Wt, bq, bk, Qb, Kb);
  k2a_z  <<<dim3(NQB, BATCH, KSPLIT), 512, 0, stream>>>(Qb, Kb, zpart);
  k2c_w  <<<dim3(NQB, BATCH, KSPLIT), 512, 0, stream>>>(Qb, Kb, zpart, wpart);
  k4_u   <<<dim3(32, BATCH), 128, 0, stream>>>(x, wpart, upart);
  k5_out <<<BATCH, 128, 0, stream>>>(upart, Wv, bv, out);
}

// Round 5
// 85.448 us; speedup vs baseline: 2.6805x; 2.6805x over previous
//
#include <hip/hip_runtime.h>

#define SLEN 4096
#define DDIM 128
#define BATCH 4
#define QB 256                 // q-rows per block (8 waves x 32 rows)
#define NQB (SLEN / QB)        // 16 q-blocks per batch
#define NW 8                   // waves per attn block (512 threads)
#define KSPLIT 8               // k-range split across blocks
#define NTILES (SLEN / 16)     // 256 k-tiles
#define TPB (NTILES / KSPLIT)  // 32 tiles per block
#define STAGE_TILES 4          // tiles per LDS stage (16 KB)
#define NSTAGES (TPB / STAGE_TILES)  // 8
#define WSLABS (NQB * NW)      // 128 colsum slabs per batch
#define SCLOG2E 0.12751743f    // log2(e)/sqrt(128)

typedef __bf16 v8bf __attribute__((ext_vector_type(8)));
typedef float f32x4 __attribute__((ext_vector_type(4)));

__device__ __forceinline__ f32x4 mfma16(v8bf a, v8bf b, f32x4 c) {
  return __builtin_amdgcn_mfma_f32_16x16x32_bf16(a, b, c, 0, 0, 0);
}

__device__ __forceinline__ void gload_lds16(const void* g, void* l) {
  __builtin_amdgcn_global_load_lds(
      (const __attribute__((address_space(1))) unsigned int*)g,
      (__attribute__((address_space(3))) unsigned int*)l, 16, 0, 0);
}

// Stage 4 K-tiles (64 rows x 256B) into LDS, XOR-swizzled (verified in R4).
// Phys slot p of row r holds logical slot p ^ (r&7); swizzle applied on the
// per-lane GLOBAL source address, LDS dest stays linear (rule #21).
__device__ __forceinline__ void stage_k(const __bf16* __restrict__ Krow0,
                                        char* buf, int wave, int lane) {
#pragma unroll
  for (int i = 0; i < 2; ++i) {
    int s = i * 512 + wave * 64 + lane;
    int r = s >> 4;
    int p = s & 15;
    int lsl = p ^ (r & 7);
    const __bf16* src = Krow0 + (size_t)r * DDIM + lsl * 8;
    char* dst = buf + (size_t)(i * 512 + wave * 64) * 16;  // wave-uniform
    gload_lds16(src, dst);
  }
}

// ---------------------------------------------------------------------------
// k0: pack Wq|Wk columns into MFMA B-fragment layout, bf16.
__global__ __launch_bounds__(256) void k0_wt(const float* __restrict__ Wq,
                                             const float* __restrict__ Wk,
                                             __bf16* __restrict__ Wt) {
  int idx = blockIdx.x * 256 + threadIdx.x;   // 0..4095
  int ct = idx >> 8;
  int hs = (idx >> 6) & 3;
  int l  = idx & 63;
  int col = ((ct & 7) << 4) + (l & 15);
  const float* W = (ct < 8) ? Wq : Wk;
  int hbase = hs * 32 + (l >> 4) * 8;
  __bf16* dst = Wt + (size_t)idx * 8;
  for (int i = 0; i < 8; ++i)
    dst[i] = (__bf16)W[(hbase + i) * DDIM + col];
}

// ---------------------------------------------------------------------------
// k1: projections Q = x@Wq + bq, K = x@Wk + bk  -> bf16, via MFMA.
__global__ __launch_bounds__(256) void k1_proj(const float* __restrict__ x,
                                               const __bf16* __restrict__ Wt,
                                               const float* __restrict__ bq,
                                               const float* __restrict__ bk,
                                               __bf16* __restrict__ Qb,
                                               __bf16* __restrict__ Kb) {
  int wave = threadIdx.x >> 6, lane = threadIdx.x & 63;
  int lr = lane & 15, lg = lane >> 4;
  int r0 = blockIdx.x * 64 + wave * 16;      // flat row over B*S
  const float* xrow = x + (size_t)(r0 + lr) * DDIM;

  v8bf xf[4];
#pragma unroll
  for (int hs = 0; hs < 4; ++hs) {
    float4 a = *reinterpret_cast<const float4*>(xrow + hs * 32 + lg * 8);
    float4 c = *reinterpret_cast<const float4*>(xrow + hs * 32 + lg * 8 + 4);
    v8bf t;
    t[0] = (__bf16)a.x; t[1] = (__bf16)a.y; t[2] = (__bf16)a.z; t[3] = (__bf16)a.w;
    t[4] = (__bf16)c.x; t[5] = (__bf16)c.y; t[6] = (__bf16)c.z; t[7] = (__bf16)c.w;
    xf[hs] = t;
  }

  for (int ct = 0; ct < 16; ++ct) {
    f32x4 acc = {0.f, 0.f, 0.f, 0.f};
#pragma unroll
    for (int hs = 0; hs < 4; ++hs) {
      v8bf wf = *reinterpret_cast<const v8bf*>(Wt + ((size_t)(ct * 4 + hs) * 64 + lane) * 8);
      acc = mfma16(xf[hs], wf, acc);
    }
    int col = ((ct & 7) << 4) + lr;
    float bias = (ct < 8) ? bq[col] : bk[col];
    __bf16* dst = (ct < 8) ? Qb : Kb;
#pragma unroll
    for (int j = 0; j < 4; ++j) {
      int row = r0 + lg * 4 + j;
      dst[(size_t)row * DDIM + col] = (__bf16)(acc[j] + bias);
    }
  }
}

// ---------------------------------------------------------------------------
// k2a: partial softmax denominators. Block (qblk,b,ks): 256 q-rows (8 waves x
// 32 disjoint rows), K-tiles staged in LDS shared by all waves, dbuf'd.
__global__ __launch_bounds__(512, 2) void k2a_z(const __bf16* __restrict__ Qb,
                                                const __bf16* __restrict__ Kb,
                                                float* __restrict__ zpart) {
  int b = blockIdx.y, qblk = blockIdx.x, ks = blockIdx.z;
  int wave = threadIdx.x >> 6, lane = threadIdx.x & 63;
  int lr = lane & 15, lg = lane >> 4;

  __shared__ __align__(16) char kbuf[2][STAGE_TILES * 16 * 256];

  const __bf16* Qbase = Qb + ((size_t)b * SLEN + qblk * QB + wave * 32) * DDIM;
  const __bf16* Kbase = Kb + ((size_t)b * SLEN + ks * TPB * 16) * DDIM;

  stage_k(Kbase, kbuf[0], wave, lane);

  v8bf qf[2][4];
#pragma unroll
  for (int qs = 0; qs < 2; ++qs)
#pragma unroll
    for (int hs = 0; hs < 4; ++hs)
      qf[qs][hs] = *reinterpret_cast<const v8bf*>(Qbase + (size_t)(qs * 16 + lr) * DDIM + hs * 32 + lg * 8);

  float zacc[2][4];
#pragma unroll
  for (int qs = 0; qs < 2; ++qs)
#pragma unroll
    for (int j = 0; j < 4; ++j) zacc[qs][j] = 0.f;

  __syncthreads();

  for (int s = 0; s < NSTAGES; ++s) {
    if (s + 1 < NSTAGES)
      stage_k(Kbase + (size_t)(s + 1) * STAGE_TILES * 16 * DDIM, kbuf[(s + 1) & 1], wave, lane);
    const char* buf = kbuf[s & 1];
#pragma unroll
    for (int t = 0; t < STAGE_TILES; ++t) {
      int r = t * 16 + lr;
      int rowbase = r * 256;
      f32x4 acc[2];
#pragma unroll
      for (int qs = 0; qs < 2; ++qs) acc[qs] = (f32x4){0.f, 0.f, 0.f, 0.f};
#pragma unroll
      for (int hs = 0; hs < 4; ++hs) {
        int slot = (hs * 4 + lg) ^ (r & 7);
        v8bf kc = *reinterpret_cast<const v8bf*>(buf + rowbase + slot * 16);
#pragma unroll
        for (int qs = 0; qs < 2; ++qs) acc[qs] = mfma16(qf[qs][hs], kc, acc[qs]);
      }
#pragma unroll
      for (int qs = 0; qs < 2; ++qs)
#pragma unroll
        for (int j = 0; j < 4; ++j)
          zacc[qs][j] += exp2f(acc[qs][j] * SCLOG2E);
    }
    __syncthreads();
  }

  // reduce over the 16 lr lanes (k columns); q-rows are wave-disjoint
#pragma unroll
  for (int qs = 0; qs < 2; ++qs)
#pragma unroll
    for (int j = 0; j < 4; ++j) {
      float z = zacc[qs][j];
      z += __shfl_xor(z, 1);
      z += __shfl_xor(z, 2);
      z += __shfl_xor(z, 4);
      z += __shfl_xor(z, 8);
      if (lr == 0)
        zpart[(((size_t)b * NQB + qblk) * KSPLIT + ks) * QB + wave * 32 + qs * 16 + lg * 4 + j] = z;
    }
}

// ---------------------------------------------------------------------------
// k2c: column weights w[k] = sum_q exp(s)/Z over this block's k-range.
__global__ __launch_bounds__(512, 2) void k2c_w(const __bf16* __restrict__ Qb,
                                                const __bf16* __restrict__ Kb,
                                                const float* __restrict__ zpart,
                                                __bf16* __restrict__ wpart) {
  int b = blockIdx.y, qblk = blockIdx.x, ks = blockIdx.z;
  int wave = threadIdx.x >> 6, lane = threadIdx.x & 63;
  int lr = lane & 15, lg = lane >> 4;

  __shared__ __align__(16) char kbuf[2][STAGE_TILES * 16 * 256];
  __shared__ float invZ[QB];

  const __bf16* Qbase = Qb + ((size_t)b * SLEN + qblk * QB + wave * 32) * DDIM;
  const __bf16* Kbase = Kb + ((size_t)b * SLEN + ks * TPB * 16) * DDIM;

  stage_k(Kbase, kbuf[0], wave, lane);

  v8bf qf[2][4];
#pragma unroll
  for (int qs = 0; qs < 2; ++qs)
#pragma unroll
    for (int hs = 0; hs < 4; ++hs)
      qf[qs][hs] = *reinterpret_cast<const v8bf*>(Qbase + (size_t)(qs * 16 + lr) * DDIM + hs * 32 + lg * 8);

  if (threadIdx.x < QB) {
    const float* zp = zpart + ((size_t)b * NQB + qblk) * KSPLIT * QB + threadIdx.x;
    float z = 0.f;
#pragma unroll
    for (int s = 0; s < KSPLIT; ++s) z += zp[(size_t)s * QB];
    invZ[threadIdx.x] = 1.0f / z;
  }

  __syncthreads();

  float iz[2][4];
#pragma unroll
  for (int qs = 0; qs < 2; ++qs)
#pragma unroll
    for (int j = 0; j < 4; ++j)
      iz[qs][j] = invZ[wave * 32 + qs * 16 + lg * 4 + j];

  __bf16* wrow = wpart + ((size_t)b * WSLABS + qblk * NW + wave) * SLEN + ks * TPB * 16;

  for (int s = 0; s < NSTAGES; ++s) {
    if (s + 1 < NSTAGES)
      stage_k(Kbase + (size_t)(s + 1) * STAGE_TILES * 16 * DDIM, kbuf[(s + 1) & 1], wave, lane);
    const char* buf = kbuf[s & 1];
#pragma unroll
    for (int t = 0; t < STAGE_TILES; ++t) {
      int r = t * 16 + lr;
      int rowbase = r * 256;
      f32x4 acc[2];
#pragma unroll
      for (int qs = 0; qs < 2; ++qs) acc[qs] = (f32x4){0.f, 0.f, 0.f, 0.f};
#pragma unroll
      for (int hs = 0; hs < 4; ++hs) {
        int slot = (hs * 4 + lg) ^ (r & 7);
        v8bf kc = *reinterpret_cast<const v8bf*>(buf + rowbase + slot * 16);
#pragma unroll
        for (int qs = 0; qs < 2; ++qs) acc[qs] = mfma16(qf[qs][hs], kc, acc[qs]);
      }
      float wk = 0.f;
#pragma unroll
      for (int qs = 0; qs < 2; ++qs)
#pragma unroll
        for (int j = 0; j < 4; ++j)
          wk += exp2f(acc[qs][j] * SCLOG2E) * iz[qs][j];
      wk += __shfl_xor(wk, 16);
      wk += __shfl_xor(wk, 32);
      if (lg == 0)
        wrow[(s * STAGE_TILES + t) * 16 + lr] = (__bf16)wk;  // disjoint per wave slab
    }
    __syncthreads();
  }
}

// ---------------------------------------------------------------------------
// k4: fused column-sum + weighted x reduction.
__global__ __launch_bounds__(128) void k4_u(const float* __restrict__ x,
                                            const __bf16* __restrict__ wpart,
                                            float* __restrict__ upart) {
  int b = blockIdx.y, c = blockIdx.x, d = threadIdx.x;
  __shared__ float ws[128];
  const __bf16* p = wpart + (size_t)b * WSLABS * SLEN + c * 128 + d;
  float s = 0.f;
  for (int j = 0; j < WSLABS; ++j) s += (float)p[(size_t)j * SLEN];
  ws[d] = s;
  __syncthreads();
  const float* xb = x + ((size_t)b * SLEN + c * 128) * DDIM;
  float acc = 0.f;
  for (int kk = 0; kk < 128; ++kk)
    acc += ws[kk] * xb[(size_t)kk * DDIM + d];
  upart[((size_t)b * 32 + c) * DDIM + d] = acc;
}

// ---------------------------------------------------------------------------
// k5: out[b,d] = (1/S) * (u[b,:] @ Wv[:,d]) + bv[d]
__global__ __launch_bounds__(128) void k5_out(const float* __restrict__ upart,
                                              const float* __restrict__ Wv,
                                              const float* __restrict__ bv,
                                              float* __restrict__ out) {
  int b = blockIdx.x, d = threadIdx.x;
  __shared__ float u[DDIM];
  float s = 0.f;
  for (int c = 0; c < 32; ++c) s += upart[((size_t)b * 32 + c) * DDIM + d];
  u[d] = s;
  __syncthreads();
  float acc = 0.f;
  for (int dp = 0; dp < DDIM; ++dp) acc += u[dp] * Wv[(size_t)dp * DDIM + d];
  out[b * DDIM + d] = acc * (1.0f / SLEN) + bv[d];
}

// ---------------------------------------------------------------------------
extern "C" void kernel_launch(void* const* d_in, const int* in_sizes, int n_in,
                              void* d_out, int out_size, void* d_ws, size_t ws_size,
                              hipStream_t stream) {
  const float* x  = (const float*)d_in[0];
  const float* Wq = (const float*)d_in[1];
  const float* bq = (const float*)d_in[2];
  const float* Wk = (const float*)d_in[3];
  const float* bk = (const float*)d_in[4];
  const float* Wv = (const float*)d_in[5];
  const float* bv = (const float*)d_in[6];
  float* out = (float*)d_out;

  char* ws = (char*)d_ws;
  __bf16* Qb    = (__bf16*)(ws);                                  // 4 MB
  __bf16* Kb    = (__bf16*)(ws + (4u << 20));                     // 4 MB
  __bf16* Wt    = (__bf16*)(ws + (8u << 20));                     // 64 KB
  __bf16* wpart = (__bf16*)(ws + (8u << 20) + (128u << 10));      // 4 MB (bf16)
  float*  zpart = (float*)(ws + (12u << 20) + (128u << 10));      // 512 KB
  float*  upart = (float*)(ws + (12u << 20) + (704u << 10));      // 16 KB

  k0_wt  <<<16, 256, 0, stream>>>(Wq, Wk, Wt);
  k1_proj<<<256, 256, 0, stream>>>(x, Wt, bq, bk, Qb, Kb);
  k2a_z  <<<dim3(NQB, BATCH, KSPLIT), 512, 0, stream>>>(Qb, Kb, zpart);
  k2c_w  <<<dim3(NQB, BATCH, KSPLIT), 512, 0, stream>>>(Qb, Kb, zpart, wpart);
  k4_u   <<<dim3(32, BATCH), 128, 0, stream>>>(x, wpart, upart);
  k5_out <<<BATCH, 128, 0, stream>>>(upart, Wv, bv, out);
}